// Round 8
// baseline (135.898 us; speedup 1.0000x reference)
//
#include <hip/hip_runtime.h>
#include <hip/hip_bf16.h>

// Problem: B=4, L=2048, D_MODEL=1024, H=16, D_QKV=64.
// Reference einsum 'bhlk,blhd->blhd' contracts k over logits only; softmax sums to 1,
// so attention output == v and the net reduces to:
//   out = x @ Wc + fc_b,  Wc[m][j] = sum_{hd} w_v[h][m][d] * fc_w[j][hd]
// Two launches:
//   prep: 1024 uniform blocks, each { cast 4 x-chunks -> bf16 } then { fold one 32x32
//         wcT tile }, XCD-local fold mapping, swizzled dbuf LDS staging.
//   final_gemm: R2-exact 128x64-tile GEMM, 1024 blocks, 4 blocks/CU (best measured).
// History: R0 prep rewrite 151->133.5. R3 fgemm dbuf+3blk/CU: 146.9 REGRESS.
//   R6 fgemm counted-vmcnt: 139.7 REGRESS. R7 fgemm XCD-swizzle: 134.6 NEUTRAL ->
//   L3-BW theory for fgemm falsified; fgemm left at R2-exact (~26us, all scheduling
//   attacks lose to simple 2-barrier + TLP).
// Round-8: prep pivot. Old prep = 256 fold blocks (1 wave/SIMD after cast drains,
//   latency-bound tail) + 128MB of 16x-redundant fcw/wv L3 re-reads. New prep: every
//   block casts AND folds (4 blk/CU TLP throughout), 32x32 fold tiles, XCD k owns
//   j-tiles 4k..4k+3 x all m (per-XCD working set ~4.5MB -> L2 hits), fold's first
//   slab load issued before the cast to hide its cold miss. Bit-identical outputs
//   (same 32-step h/ks-ascending MFMA chain per wcT element; same cast math).

typedef __attribute__((ext_vector_type(8))) short bf16x8;
typedef __attribute__((ext_vector_type(4))) float f32x4;

__device__ __forceinline__ f32x4 mfma16(bf16x8 a, bf16x8 b, f32x4 c) {
  return __builtin_amdgcn_mfma_f32_16x16x32_bf16(a, b, c, 0, 0, 0);
}

// fp32 -> bf16 bits, round-to-nearest-even
__device__ __forceinline__ unsigned short f2b(float f) {
  unsigned int u = __builtin_bit_cast(unsigned int, f);
  return (unsigned short)((u + 0x7fffu + ((u >> 16) & 1u)) >> 16);
}

__device__ __forceinline__ bf16x8 cvt8(float4 a, float4 b) {
  bf16x8 r;
  r[0] = (short)f2b(a.x); r[1] = (short)f2b(a.y); r[2] = (short)f2b(a.z); r[3] = (short)f2b(a.w);
  r[4] = (short)f2b(b.x); r[5] = (short)f2b(b.y); r[6] = (short)f2b(b.z); r[7] = (short)f2b(b.w);
  return r;
}

// async global->LDS, 16 B per lane (m97 pattern; LDS dest = wave-uniform base + lane*16)
__device__ __forceinline__ void gld_lds16(const void* g, void* l) {
  __builtin_amdgcn_global_load_lds((const __attribute__((address_space(1))) unsigned int*)g,
                                   (__attribute__((address_space(3))) unsigned int*)l, 16, 0, 0);
}

// prep: 1024 blocks. Each block: cast 4 chunks of x (8192 elems), then fold one 32x32
// tile of wcT[j][m] = sum_{h,d} fcw[j][h*64+d] * wv[h][m][d].
__global__ __launch_bounds__(256) void prep(const float* __restrict__ x,
                                            const float* __restrict__ wv,
                                            const float* __restrict__ fcw,
                                            unsigned short* __restrict__ xb,
                                            unsigned short* __restrict__ wcT) {
  // Fold LDS: per-h 32x64 bf16 slabs of A=fcw rows and B=wv rows, double-buffered (16KB).
  // XOR swizzle (row&7)<<4 on the in-row byte: stride-128B frag reads stay <=2-way.
  __shared__ __align__(16) short As[2][32 * 64];
  __shared__ __align__(16) short Bs[2][32 * 64];

  int bid = blockIdx.x, t = threadIdx.x;
  int wid = t >> 6, lane = t & 63, l16 = lane & 15, quad = lane >> 4;

  // Fold tile mapping, XCD-local (XCD = bid%8 under round-robin dispatch):
  // XCD k owns j-tiles {4k..4k+3} x all 32 m-tiles -> ~4.5MB/XCD, re-reads hit L2.
  int k8 = bid & 7, a = bid >> 3;
  int j0 = (k8 * 4 + (a & 3)) * 32;   // j tile (32 rows of fcw / wcT)
  int m0 = (a >> 2) * 32;             // m tile (32 rows of wv-as-[m][d])
  int fr = wid >> 1, fc = wid & 1;    // wave -> 16x16 frag of the 32x32 tile
  int rowt = t >> 3, colb = (t & 7) * 8;  // staging: row 0..31, 8-float segment

  float4 ra[2], rb[2];  // in-flight h-slab (per thread: 8 floats of A, 8 of B)

#define LOADH(h)                                                                     \
    {                                                                                \
      const float* pa = fcw + (j0 + rowt) * 1024 + (h) * 64 + colb;                  \
      ra[0] = *reinterpret_cast<const float4*>(pa);                                  \
      ra[1] = *reinterpret_cast<const float4*>(pa + 4);                              \
      const float* pb = wv + (h) * 65536 + (m0 + rowt) * 64 + colb;                  \
      rb[0] = *reinterpret_cast<const float4*>(pb);                                  \
      rb[1] = *reinterpret_cast<const float4*>(pb + 4);                              \
    }
#define STOREH(buf)                                                                  \
    {                                                                                \
      int bo = rowt * 128 + ((colb * 2) ^ ((rowt & 7) << 4));                        \
      *reinterpret_cast<bf16x8*>((char*)As[buf] + bo) = cvt8(ra[0], ra[1]);          \
      *reinterpret_cast<bf16x8*>((char*)Bs[buf] + bo) = cvt8(rb[0], rb[1]);          \
    }

  LOADH(0);  // issue-early: fold's cold miss hides under the cast

  // cast: 4 contiguous chunks (8 rows of x), 16-B ld / 16-B st per lane
#pragma unroll
  for (int i = 0; i < 4; i++) {
    int idx = (bid * 4 + i) * 2048 + t * 8;
    float4 ca = *reinterpret_cast<const float4*>(x + idx);
    float4 cb = *reinterpret_cast<const float4*>(x + idx + 4);
    *reinterpret_cast<bf16x8*>(xb + idx) = cvt8(ca, cb);
  }

  STOREH(0);
  __syncthreads();

  f32x4 acc = (f32x4){0.f, 0.f, 0.f, 0.f};
  int rowfa = fr * 16 + l16, rxa = (rowfa & 7) << 4, rba = rowfa * 128;
  int rowfb = fc * 16 + l16, rxb = (rowfb & 7) << 4, rbb = rowfb * 128;

  for (int h = 0; h < 16; ++h) {
    int cur = h & 1;
    if (h < 15) LOADH(h + 1);  // issue-early: HBM/L2 latency hides under frags + MFMA

    bf16x8 af0 = *reinterpret_cast<const bf16x8*>((char*)As[cur] + rba + ((quad * 16) ^ rxa));
    bf16x8 af1 = *reinterpret_cast<const bf16x8*>((char*)As[cur] + rba + ((64 + quad * 16) ^ rxa));
    bf16x8 bg0 = *reinterpret_cast<const bf16x8*>((char*)Bs[cur] + rbb + ((quad * 16) ^ rxb));
    bf16x8 bg1 = *reinterpret_cast<const bf16x8*>((char*)Bs[cur] + rbb + ((64 + quad * 16) ^ rxb));
    acc = mfma16(af0, bg0, acc);   // ks=0 then ks=1: same k-ascending chain as before
    acc = mfma16(af1, bg1, acc);

    if (h < 15) STOREH(cur ^ 1);   // write-late into the other buffer
    __syncthreads();
  }
#undef LOADH
#undef STOREH

  // C/D layout: col=lane&15, row=(lane>>4)*4+r
  int jj = j0 + fr * 16 + quad * 4;
  int mm = m0 + fc * 16 + l16;
#pragma unroll
  for (int r = 0; r < 4; r++) wcT[(jj + r) * 1024 + mm] = f2b(acc[r]);
}

// out[i][j] = sum_m xb[i][m]*wcT[j][m] + fcb[j].  M=8192,N=1024,K=1024.
// 128x64 tile, BK=64 (two 32-k slabs), 1024 blocks N-fastest (16 blocks share an A M-tile).
// R2-exact structure (best measured: 133.5 total): stage->sync->compute, 24KB LDS,
// 4 blocks/CU. R3/R6/R7 scheduling+locality attacks all regressed or were neutral.
__global__ __launch_bounds__(256, 4) void final_gemm(const unsigned short* __restrict__ xb,
                                                     const unsigned short* __restrict__ wcT,
                                                     const float* __restrict__ fcb,
                                                     float* __restrict__ out) {
  __shared__ __align__(16) unsigned short As[2 * 128 * 32];  // 16 KB  [slab][row][32]
  __shared__ __align__(16) unsigned short Bs[2 * 64 * 32];   //  8 KB
  int t = threadIdx.x, wid = t >> 6, lane = t & 63, l16 = lane & 15, quad = lane >> 4;
  int wr = wid >> 1, wc = wid & 1;
  int row0 = (blockIdx.x >> 4) * 128;   // M tile (64)
  int col0 = (blockIdx.x & 15) * 64;    // N tile (16) — fastest: B stays L2-hot

  // A staging: 16 x 1KB chunks; blk = wid*4+j: slab blk>>3, rows (blk&7)*16 + lane>>2, kq lane&3.
  // B staging:  8 x 1KB chunks; blk = wid*2+j: slab blk>>2, rows (blk&3)*16 + lane>>2, kq lane&3.
  int w4 = wid * 4, w2 = wid * 2;
  const unsigned short* Ap[4];
  const unsigned short* Bp[2];
#pragma unroll
  for (int j = 0; j < 4; j++) {
    int blk = w4 + j, s = blk >> 3;
    int row = (blk & 7) * 16 + (lane >> 2), kq = lane & 3;
    Ap[j] = xb + (row0 + row) * 1024 + s * 32 + kq * 8;
  }
#pragma unroll
  for (int j = 0; j < 2; j++) {
    int blk = w2 + j, s = blk >> 2;
    int row = (blk & 3) * 16 + (lane >> 2), kq = lane & 3;
    Bp[j] = wcT + (col0 + row) * 1024 + s * 32 + kq * 8;
  }

  f32x4 acc[4][2];
#pragma unroll
  for (int rt = 0; rt < 4; rt++)
#pragma unroll
    for (int ct = 0; ct < 2; ct++) acc[rt][ct] = (f32x4){0.f, 0.f, 0.f, 0.f};

  for (int k0 = 0; k0 < 1024; k0 += 64) {
    __syncthreads();
#pragma unroll
    for (int j = 0; j < 4; j++) gld_lds16(Ap[j] + k0, &As[(w4 + j) * 512 + lane * 8]);
#pragma unroll
    for (int j = 0; j < 2; j++) gld_lds16(Bp[j] + k0, &Bs[(w2 + j) * 512 + lane * 8]);
    __syncthreads();
#pragma unroll
    for (int s = 0; s < 2; s++) {
      bf16x8 af[4], bfr[2];
#pragma unroll
      for (int rt = 0; rt < 4; rt++)
        af[rt] = *reinterpret_cast<const bf16x8*>(&As[s * 4096 + (wr * 64 + rt * 16 + l16) * 32 + quad * 8]);
#pragma unroll
      for (int ct = 0; ct < 2; ct++)
        bfr[ct] = *reinterpret_cast<const bf16x8*>(&Bs[s * 2048 + (wc * 32 + ct * 16 + l16) * 32 + quad * 8]);
#pragma unroll
      for (int rt = 0; rt < 4; rt++)
#pragma unroll
        for (int ct = 0; ct < 2; ct++)
          acc[rt][ct] = mfma16(af[rt], bfr[ct], acc[rt][ct]);
    }
  }

#pragma unroll
  for (int ct = 0; ct < 2; ct++) {
    int j = col0 + wc * 32 + ct * 16 + l16;
    float bias = fcb[j];
#pragma unroll
    for (int rt = 0; rt < 4; rt++) {
      int i0 = row0 + wr * 64 + rt * 16 + quad * 4;
      f32x4 a = acc[rt][ct];
#pragma unroll
      for (int r = 0; r < 4; r++) out[(i0 + r) * 1024 + j] = a[r] + bias;
    }
  }
}

extern "C" void kernel_launch(void* const* d_in, const int* in_sizes, int n_in,
                              void* d_out, int out_size, void* d_ws, size_t ws_size,
                              hipStream_t stream) {
  const float* x   = (const float*)d_in[0];
  // d_in[1] mask, d_in[2] w_q, d_in[3] w_k: dead per reference semantics
  const float* wv  = (const float*)d_in[4];
  const float* fcw = (const float*)d_in[5];
  const float* fcb = (const float*)d_in[6];
  float* out = (float*)d_out;

  char* ws = (char*)d_ws;
  unsigned short* xb  = (unsigned short*)(ws);              // 16 MB (8192x1024 bf16)
  unsigned short* wcT = (unsigned short*)(ws + 16777216);   // 2 MB  (1024x1024 bf16)

  prep<<<1024, 256, 0, stream>>>(x, wv, fcw, xb, wcT);
  final_gemm<<<1024, 256, 0, stream>>>(xb, wcT, fcb, out);
}